// Round 5
// baseline (580.182 us; speedup 1.0000x reference)
//
#include <hip/hip_runtime.h>
#include <hip/hip_bf16.h>

#define N_NODES 20000
#define T_STEPS 8
#define E_EDGES 320000
#define HID 128
#define BN 32                          // nodes per gru block: 625 blocks exactly

typedef short short8 __attribute__((ext_vector_type(8)));
typedef float f32x4 __attribute__((ext_vector_type(4)));

// ---- all scratch in device globals: independent of ws_size ----------------
__device__ __attribute__((aligned(16))) float g_xT[T_STEPS * N_NODES];
__device__ __attribute__((aligned(16))) float g_ndf[T_STEPS * N_NODES * 4];
__device__ __attribute__((aligned(16))) int   g_cnt[N_NODES];
__device__ __attribute__((aligned(16))) int   g_rowptr[N_NODES + 1];
__device__ __attribute__((aligned(16))) int   g_cursor[N_NODES];
__device__ __attribute__((aligned(16))) int   g_sorted[E_EDGES];
__device__ __attribute__((aligned(16))) short g_w1hi[65536];
__device__ __attribute__((aligned(16))) short g_w1lo[65536];
__device__ __attribute__((aligned(16))) short g_w2hi[32768];
__device__ __attribute__((aligned(16))) short g_w2lo[32768];
__device__ float g_lin[6];            // P,Q,R per head
__device__ int   g_flag;

__device__ __forceinline__ float fsig(float z) {
    return 1.0f / (1.0f + __expf(-z));
}
__device__ __forceinline__ unsigned short f2bf(float f) {
    unsigned u = __builtin_bit_cast(unsigned, f);
    unsigned r = (u + 0x7FFFu + ((u >> 16) & 1u)) >> 16;   // RTNE
    return (unsigned short)r;
}
__device__ __forceinline__ float bf2f(unsigned short s) {
    return __builtin_bit_cast(float, ((unsigned)s) << 16);
}

// ---------------------------------------------------------------------------
__global__ void detect_kernel(const unsigned int* __restrict__ ei32) {
    int all_zero = 1;
    for (int k = 0; k < 64; ++k)
        if (ei32[2 * k + 1] != 0u) { all_zero = 0; break; }
    g_flag = all_zero;   // 1 => int64 layout
}

__device__ __forceinline__ void load_edge(const void* ei, int e, int& src, int& dst) {
    if (g_flag) {
        const long long* p = (const long long*)ei;
        src = (int)p[e]; dst = (int)p[E_EDGES + e];
    } else {
        const int* p = (const int*)ei;
        src = p[e]; dst = p[E_EDGES + e];
    }
}

// ---------------------------------------------------------------------------
// init: transpose x -> xT[t][n]; zero histogram; count in-degrees (hist).
// grid covers 320000 threads.
// ---------------------------------------------------------------------------
__global__ __launch_bounds__(256) void init_kernel(
    const float* __restrict__ x, const void* __restrict__ ei)
{
    const int i = blockIdx.x * 256 + threadIdx.x;
    if (i < T_STEPS * N_NODES) {
        const int n = i >> 3, t = i & 7;
        g_xT[t * N_NODES + n] = x[i];
    }
    if (i < N_NODES) g_cnt[i] = 0;
    __threadfence();   // cnt zeros visible before any hist increments? same kernel:
    // NOTE: zero+increment of g_cnt in one kernel is racy across blocks; instead
    // hist increments go to a separate pass below via atomic on pre-zeroed g_cnt.
}

__global__ __launch_bounds__(256) void hist_kernel(const void* __restrict__ ei) {
    const int e = blockIdx.x * 256 + threadIdx.x;
    if (e >= E_EDGES) return;
    int src, dst; load_edge(ei, e, src, dst);
    atomicAdd(&g_cnt[dst], 1);
}

// single block, 1024 threads: exclusive scan of g_cnt -> g_rowptr, g_cursor
__global__ __launch_bounds__(1024) void scan_kernel() {
    __shared__ int part[1024];
    const int tid  = threadIdx.x;
    const int base = tid * 20;
    int local[20];
    int s = 0;
    #pragma unroll
    for (int i = 0; i < 20; ++i) {
        const int n = base + i;
        const int c = (n < N_NODES) ? g_cnt[n] : 0;
        local[i] = s; s += c;
    }
    part[tid] = s;
    __syncthreads();
    for (int off = 1; off < 1024; off <<= 1) {
        const int v = (tid >= off) ? part[tid - off] : 0;
        __syncthreads();
        part[tid] += v;
        __syncthreads();
    }
    const int pre = (tid == 0) ? 0 : part[tid - 1];
    #pragma unroll
    for (int i = 0; i < 20; ++i) {
        const int n = base + i;
        if (n < N_NODES) {
            const int v = pre + local[i];
            g_rowptr[n] = v;
            g_cursor[n] = v;
        }
    }
    if (tid == 1023) g_rowptr[N_NODES] = part[1023];
}

__global__ __launch_bounds__(256) void scatter_kernel(const void* __restrict__ ei) {
    const int e = blockIdx.x * 256 + threadIdx.x;
    if (e >= E_EDGES) return;
    int src, dst; load_edge(ei, e, src, dst);
    const int pos = atomicAdd(&g_cursor[dst], 1);
    g_sorted[pos] = src;
}

// ---------------------------------------------------------------------------
// Prep: pack transposed bf16 hi/lo W1,W2 fragments; compute P,Q,R per head.
// ---------------------------------------------------------------------------
__global__ __launch_bounds__(256) void prep_kernel(
    const float* __restrict__ W1, const float* __restrict__ W2,
    const float* __restrict__ W_l, const float* __restrict__ b_l,
    const float* __restrict__ W_r, const float* __restrict__ b_r,
    const float* __restrict__ att)
{
    int i = blockIdx.x * 256 + threadIdx.x;   // 0 .. 98303
    if (i < 65536) {                          // W1: (256,256) [k][n]
        int k = i >> 8, n = i & 255;
        float w = W1[i];
        int kb = k >> 5, kq = (k >> 3) & 3, r = k & 7;
        int idx = ((kb * 256 + n) * 4 + kq) * 8 + r;
        unsigned short hi = f2bf(w);
        g_w1hi[idx] = (short)hi;
        g_w1lo[idx] = (short)f2bf(w - bf2f(hi));
    } else {                                  // W2: (256,128) [k][n]
        int j = i - 65536;
        int k = j >> 7, n = j & 127;
        float w = W2[j];
        int kb = k >> 5, kq = (k >> 3) & 3, r = k & 7;
        int idx = ((kb * 128 + n) * 4 + kq) * 8 + r;
        unsigned short hi = f2bf(w);
        g_w2hi[idx] = (short)hi;
        g_w2lo[idx] = (short)f2bf(w - bf2f(hi));
    }
    if (blockIdx.x == 0 && threadIdx.x < 2) {
        const int hh = threadIdx.x;
        float P = 0.f, Q = 0.f, R = 0.f;
        for (int k = 0; k < 64; ++k) {
            const int c = hh * 64 + k;
            const float a = att[c];
            P = fmaf(a, W_l[c], P);
            Q = fmaf(a, W_r[c], Q);
            R = fmaf(a, b_l[c] + b_r[c], R);
        }
        g_lin[hh * 3 + 0] = P;
        g_lin[hh * 3 + 1] = Q;
        g_lin[hh * 3 + 2] = R;
    }
}

// ---------------------------------------------------------------------------
// Edge pass, all 8 timesteps, no atomics (same as r4).
// ---------------------------------------------------------------------------
__global__ __launch_bounds__(256) void edge_all_kernel(
    const float* __restrict__ W_l, const float* __restrict__ b_l,
    const float* __restrict__ W_r, const float* __restrict__ b_r,
    const float* __restrict__ att)
{
    __shared__ float4 ch4[128];
    const int tid = threadIdx.x;
    if (tid < 128)
        ch4[tid] = make_float4(W_l[tid], W_r[tid], b_l[tid] + b_r[tid], att[tid]);
    __syncthreads();

    const int n    = blockIdx.x * 128 + (tid >> 1);
    const int head = tid & 1;
    const int t    = blockIdx.y;
    if (n >= N_NODES) return;

    const float* xrow = &g_xT[t * N_NODES];
    const float xd = xrow[n];
    const float P = g_lin[head * 3 + 0];
    const float Q = g_lin[head * 3 + 1];
    const float R = g_lin[head * 3 + 2];
    const float4* chh = &ch4[head * 64];

    const int base = g_rowptr[n];
    const int deg  = g_rowptr[n + 1] - base;
    const int tot  = deg + 1;            // +1 = self loop at idx 0

    float den = 0.f, num = 0.f;
    for (int cs = 0; cs < tot; cs += 8) {
        int m = tot - cs; if (m > 8) m = 8;
        float xs[8];
        #pragma unroll
        for (int e = 0; e < 8; ++e) {
            xs[e] = 0.f;
            if (e < m) {
                const int idx = cs + e;
                xs[e] = (idx == 0) ? xd : xrow[g_sorted[base + idx - 1]];
            }
        }
        float ea[8];
        #pragma unroll
        for (int e = 0; e < 8; ++e) ea[e] = 0.f;
        #pragma unroll 4
        for (int c = 0; c < 64; ++c) {
            const float4 f = chh[c];
            const float dpart = fmaf(xd, f.y, f.z);
            #pragma unroll
            for (int e = 0; e < 8; ++e) {
                const float a = fmaf(xs[e], f.x, dpart);
                ea[e] = fmaf(fabsf(a), f.w, ea[e]);
            }
        }
        #pragma unroll
        for (int e = 0; e < 8; ++e) {
            if (e < m) {
                const float ee = fmaf(0.6f, fmaf(xs[e], P, fmaf(xd, Q, R)), 0.4f * ea[e]);
                const float ex = __expf(ee);
                den += ex;
                num = fmaf(ex, xs[e], num);
            }
        }
    }
    g_ndf[((size_t)t * N_NODES + n) * 4 + head]     = den;
    g_ndf[((size_t)t * N_NODES + n) * 4 + 2 + head] = num;
}

// ---------------------------------------------------------------------------
// GRU v2: BN=32, 625 blocks, 512 threads. h in REGISTERS. featA row = 512
// shorts: segments [f0: g0-15 | h: g16-31 | rh: g32-47 | f1: g48-63], XOR
// granule swizzle ^ (node&7) within segment. 2 barriers/step.
// ---------------------------------------------------------------------------
__global__ __launch_bounds__(512, 4) void gru_all_kernel(
    const float* __restrict__ W_l, const float* __restrict__ b_l,
    const float* __restrict__ conv_bias,
    const float* __restrict__ b1, const float* __restrict__ b2,
    float* __restrict__ hout)
{
    __shared__ short featA[BN * 512];   // 32768 B
    __shared__ float swl[128], sbl[128], scb[128], sb1a[128], sb1b[128], sb2[128];

    const int t   = threadIdx.x;
    const int n0g = blockIdx.x * BN;

    if (t < 128) {
        swl[t] = W_l[t]; sbl[t] = b_l[t]; scb[t] = conv_bias[t];
        sb1a[t] = b1[t]; sb1b[t] = b1[128 + t]; sb2[t] = b2[t];
    }
    // zero h segment (granules 16..31), one granule per thread
    {
        const int node = t >> 4;
        const int g    = 16 + (t & 15);
        const int gsw  = g ^ (node & 7);
        *(short8*)&featA[node * 512 + gsw * 8] = (short8)0;
    }
    __syncthreads();   // biases + h-zero visible

    const int wid = t >> 6;
    const int l   = t & 63;
    const int lr  = l & 15;
    const int lk  = l >> 4;
    const int ec  = wid * 16 + lr;      // this wave's column set
    const int pnode = t >> 4;           // phase0 mapping
    const int pg    = t & 15;

    const float ba1 = sb1a[ec], bb1 = sb1b[ec], bb2 = sb2[ec];

    f32x4 hreg[2], ureg[2];
    hreg[0] = (f32x4){0.f, 0.f, 0.f, 0.f};
    hreg[1] = (f32x4){0.f, 0.f, 0.f, 0.f};

    for (int step = 0; step < T_STEPS; ++step) {
        const int fbase = (step & 1) ? 48 : 0;

        // ---- phase0: f for this step -> segment fbase (512 tasks) --------
        {
            const int head = pg >> 3;
            const size_t bi = ((size_t)step * N_NODES + n0g + pnode) * 4;
            const float den = g_ndf[bi + head];
            const float num = g_ndf[bi + 2 + head];
            const float inv = 1.0f / (den + 1e-16f);
            short8 v;
            #pragma unroll
            for (int r = 0; r < 8; ++r) {
                const int c = pg * 8 + r;
                const float z = (num * swl[c] + den * sbl[c]) * inv + scb[c];
                v[r] = (short)f2bf(fsig(z));
            }
            const int gsw = (fbase + pg) ^ (pnode & 7);
            *(short8*)&featA[pnode * 512 + gsw * 8] = v;
        }
        __syncthreads();   // B1: f[p] + h (prev epi2) visible to all

        // ---- GEMM1: M=32, this wave cols ec (r) and 128+ec (u), K=256 ----
        f32x4 acc0[2], acc1[2];
        #pragma unroll
        for (int mf = 0; mf < 2; ++mf) {
            acc0[mf] = (f32x4){ba1, ba1, ba1, ba1};
            acc1[mf] = (f32x4){bb1, bb1, bb1, bb1};
        }
        #pragma unroll
        for (int kb = 0; kb < 8; ++kb) {
            const int glin = kb * 4 + lk;                 // 0..31
            const int gra  = (glin < 16) ? fbase + glin : glin;  // h at 16..31
            short8 ah[2];
            #pragma unroll
            for (int mf = 0; mf < 2; ++mf) {
                const int row = mf * 16 + lr;
                const int g   = gra ^ (row & 7);
                ah[mf] = *(short8*)&featA[row * 512 + g * 8];
            }
            const int bidx0 = ((kb * 256 + ec) * 4 + lk) * 8;
            const int bidx1 = bidx0 + 4096;               // +128 cols
            const short8 bh0 = *(const short8*)&g_w1hi[bidx0];
            const short8 bl0 = *(const short8*)&g_w1lo[bidx0];
            const short8 bh1 = *(const short8*)&g_w1hi[bidx1];
            const short8 bl1 = *(const short8*)&g_w1lo[bidx1];
            #pragma unroll
            for (int mf = 0; mf < 2; ++mf) {
                acc0[mf] = __builtin_amdgcn_mfma_f32_16x16x32_bf16(ah[mf], bh0, acc0[mf], 0, 0, 0);
                acc0[mf] = __builtin_amdgcn_mfma_f32_16x16x32_bf16(ah[mf], bl0, acc0[mf], 0, 0, 0);
                acc1[mf] = __builtin_amdgcn_mfma_f32_16x16x32_bf16(ah[mf], bh1, acc1[mf], 0, 0, 0);
                acc1[mf] = __builtin_amdgcn_mfma_f32_16x16x32_bf16(ah[mf], bl1, acc1[mf], 0, 0, 0);
            }
        }

        // ---- epi1: r,u; rh -> rh segment (packed dword writes) -----------
        #pragma unroll
        for (int mf = 0; mf < 2; ++mf) {
            #pragma unroll
            for (int j = 0; j < 4; ++j) {
                const int row = mf * 16 + lk * 4 + j;
                const float r = fsig(acc0[mf][j]);
                const float u = fsig(acc1[mf][j]);
                ureg[mf][j] = u;
                const float rh = r * hreg[mf][j];
                const float ot = __shfl_xor(rh, 1);
                if ((lr & 1) == 0) {
                    const unsigned pk = (unsigned)f2bf(rh) | ((unsigned)f2bf(ot) << 16);
                    const int g  = (32 + (ec >> 3)) ^ (row & 7);
                    const int ad = row * 512 + g * 8 + (ec & 7);
                    *(unsigned*)&featA[ad] = pk;
                }
            }
        }
        __syncthreads();   // B2: rh visible to all

        // ---- GEMM2: this wave col ec, K=256 ------------------------------
        f32x4 acc2[2];
        #pragma unroll
        for (int mf = 0; mf < 2; ++mf)
            acc2[mf] = (f32x4){bb2, bb2, bb2, bb2};
        #pragma unroll
        for (int kb = 0; kb < 8; ++kb) {
            const int glin = kb * 4 + lk;
            const int gra  = (glin < 16) ? fbase + glin : glin + 16;  // rh at 32..47
            short8 ah[2];
            #pragma unroll
            for (int mf = 0; mf < 2; ++mf) {
                const int row = mf * 16 + lr;
                const int g   = gra ^ (row & 7);
                ah[mf] = *(short8*)&featA[row * 512 + g * 8];
            }
            const int bidx = ((kb * 128 + ec) * 4 + lk) * 8;
            const short8 bh = *(const short8*)&g_w2hi[bidx];
            const short8 bl = *(const short8*)&g_w2lo[bidx];
            #pragma unroll
            for (int mf = 0; mf < 2; ++mf) {
                acc2[mf] = __builtin_amdgcn_mfma_f32_16x16x32_bf16(ah[mf], bh, acc2[mf], 0, 0, 0);
                acc2[mf] = __builtin_amdgcn_mfma_f32_16x16x32_bf16(ah[mf], bl, acc2[mf], 0, 0, 0);
            }
        }

        // ---- epi2: c=tanh; h_new = c + u*(h-c); h -> h segment -----------
        #pragma unroll
        for (int mf = 0; mf < 2; ++mf) {
            #pragma unroll
            for (int j = 0; j < 4; ++j) {
                const int row = mf * 16 + lk * 4 + j;
                const float c  = tanhf(acc2[mf][j]);
                const float hn = fmaf(ureg[mf][j], hreg[mf][j] - c, c);
                hreg[mf][j] = hn;
                if (step < T_STEPS - 1) {
                    const float ot = __shfl_xor(hn, 1);
                    if ((lr & 1) == 0) {
                        const unsigned pk = (unsigned)f2bf(hn) | ((unsigned)f2bf(ot) << 16);
                        const int g  = (16 + (ec >> 3)) ^ (row & 7);
                        const int ad = row * 512 + g * 8 + (ec & 7);
                        *(unsigned*)&featA[ad] = pk;
                    }
                } else {
                    hout[(size_t)(n0g + row) * HID + ec] = hn;
                }
            }
        }
        // no barrier: next phase0 writes f[p^1] (disjoint); B1 fences all.
    }
}

// ---------------------------------------------------------------------------
extern "C" void kernel_launch(void* const* d_in, const int* in_sizes, int n_in,
                              void* d_out, int out_size, void* d_ws, size_t ws_size,
                              hipStream_t stream) {
    const float* x   = (const float*)d_in[0];
    const void*  ei  = d_in[1];
    // d_in[2] edge_weight: unused by the reference
    const float* W_l = (const float*)d_in[3];
    const float* b_l = (const float*)d_in[4];
    const float* W_r = (const float*)d_in[5];
    const float* b_r = (const float*)d_in[6];
    const float* att = (const float*)d_in[7];
    const float* cb  = (const float*)d_in[8];
    const float* W1  = (const float*)d_in[9];
    const float* b1  = (const float*)d_in[10];
    const float* W2  = (const float*)d_in[11];
    const float* b2  = (const float*)d_in[12];

    float* h = (float*)d_out;
    (void)d_ws; (void)ws_size;

    detect_kernel<<<1, 1, 0, stream>>>((const unsigned int*)ei);
    init_kernel<<<(T_STEPS * N_NODES + 255) / 256, 256, 0, stream>>>(x, ei);
    hist_kernel<<<(E_EDGES + 255) / 256, 256, 0, stream>>>(ei);
    scan_kernel<<<1, 1024, 0, stream>>>();
    scatter_kernel<<<(E_EDGES + 255) / 256, 256, 0, stream>>>(ei);
    prep_kernel<<<384, 256, 0, stream>>>(W1, W2, W_l, b_l, W_r, b_r, att);
    edge_all_kernel<<<dim3(157, T_STEPS), 256, 0, stream>>>(W_l, b_l, W_r, b_r, att);
    gru_all_kernel<<<N_NODES / BN, 512, 0, stream>>>(W_l, b_l, cb, b1, b2, h);
}

// Round 6
// 419.172 us; speedup vs baseline: 1.3841x; 1.3841x over previous
//
#include <hip/hip_runtime.h>
#include <hip/hip_bf16.h>

#define N_NODES 20000
#define T_STEPS 8
#define E_EDGES 320000
#define HID 128
#define BN 32                          // nodes per gru block: 625 blocks exactly

typedef short short8 __attribute__((ext_vector_type(8)));
typedef float f32x4 __attribute__((ext_vector_type(4)));

// ---- all scratch in device globals: independent of ws_size ----------------
__device__ __attribute__((aligned(16))) float g_xT[T_STEPS * N_NODES];
__device__ __attribute__((aligned(16))) float g_ndf[T_STEPS * N_NODES * 4];
__device__ __attribute__((aligned(16))) int   g_cnt[N_NODES];
__device__ __attribute__((aligned(16))) int   g_rowptr[N_NODES + 1];
__device__ __attribute__((aligned(16))) int   g_cursor[N_NODES];
__device__ __attribute__((aligned(16))) int   g_sorted[E_EDGES];
__device__ __attribute__((aligned(16))) short g_w1hi[65536];
__device__ __attribute__((aligned(16))) short g_w1lo[65536];
__device__ __attribute__((aligned(16))) short g_w2hi[32768];
__device__ __attribute__((aligned(16))) short g_w2lo[32768];
__device__ float g_lin[6];            // P,Q,R per head
__device__ int   g_flag;

__device__ __forceinline__ float fsig(float z) {
    return 1.0f / (1.0f + __expf(-z));
}
__device__ __forceinline__ unsigned short f2bf(float f) {
    unsigned u = __builtin_bit_cast(unsigned, f);
    unsigned r = (u + 0x7FFFu + ((u >> 16) & 1u)) >> 16;   // RTNE
    return (unsigned short)r;
}
__device__ __forceinline__ float bf2f(unsigned short s) {
    return __builtin_bit_cast(float, ((unsigned)s) << 16);
}

// ---------------------------------------------------------------------------
__global__ void detect_kernel(const unsigned int* __restrict__ ei32) {
    int all_zero = 1;
    for (int k = 0; k < 64; ++k)
        if (ei32[2 * k + 1] != 0u) { all_zero = 0; break; }
    g_flag = all_zero;   // 1 => int64 layout
}

__device__ __forceinline__ void load_edge(const void* ei, int e, int& src, int& dst) {
    if (g_flag) {
        const long long* p = (const long long*)ei;
        src = (int)p[e]; dst = (int)p[E_EDGES + e];
    } else {
        const int* p = (const int*)ei;
        src = p[e]; dst = p[E_EDGES + e];
    }
}

// ---------------------------------------------------------------------------
// init: transpose x -> xT[t][n]; zero histogram.
// ---------------------------------------------------------------------------
__global__ __launch_bounds__(256) void init_kernel(
    const float* __restrict__ x, const void* __restrict__ ei)
{
    const int i = blockIdx.x * 256 + threadIdx.x;
    if (i < T_STEPS * N_NODES) {
        const int n = i >> 3, t = i & 7;
        g_xT[t * N_NODES + n] = x[i];
    }
    if (i < N_NODES) g_cnt[i] = 0;
}

__global__ __launch_bounds__(256) void hist_kernel(const void* __restrict__ ei) {
    const int e = blockIdx.x * 256 + threadIdx.x;
    if (e >= E_EDGES) return;
    int src, dst; load_edge(ei, e, src, dst);
    atomicAdd(&g_cnt[dst], 1);
}

// single block, 1024 threads: exclusive scan of g_cnt -> g_rowptr, g_cursor
__global__ __launch_bounds__(1024) void scan_kernel() {
    __shared__ int part[1024];
    const int tid  = threadIdx.x;
    const int base = tid * 20;
    int local[20];
    int s = 0;
    #pragma unroll
    for (int i = 0; i < 20; ++i) {
        const int n = base + i;
        const int c = (n < N_NODES) ? g_cnt[n] : 0;
        local[i] = s; s += c;
    }
    part[tid] = s;
    __syncthreads();
    for (int off = 1; off < 1024; off <<= 1) {
        const int v = (tid >= off) ? part[tid - off] : 0;
        __syncthreads();
        part[tid] += v;
        __syncthreads();
    }
    const int pre = (tid == 0) ? 0 : part[tid - 1];
    #pragma unroll
    for (int i = 0; i < 20; ++i) {
        const int n = base + i;
        if (n < N_NODES) {
            const int v = pre + local[i];
            g_rowptr[n] = v;
            g_cursor[n] = v;
        }
    }
    if (tid == 1023) g_rowptr[N_NODES] = part[1023];
}

__global__ __launch_bounds__(256) void scatter_kernel(const void* __restrict__ ei) {
    const int e = blockIdx.x * 256 + threadIdx.x;
    if (e >= E_EDGES) return;
    int src, dst; load_edge(ei, e, src, dst);
    const int pos = atomicAdd(&g_cursor[dst], 1);
    g_sorted[pos] = src;
}

// ---------------------------------------------------------------------------
// Prep: pack transposed bf16 hi/lo W1,W2 fragments; compute P,Q,R per head.
// ---------------------------------------------------------------------------
__global__ __launch_bounds__(256) void prep_kernel(
    const float* __restrict__ W1, const float* __restrict__ W2,
    const float* __restrict__ W_l, const float* __restrict__ b_l,
    const float* __restrict__ W_r, const float* __restrict__ b_r,
    const float* __restrict__ att)
{
    int i = blockIdx.x * 256 + threadIdx.x;   // 0 .. 98303
    if (i < 65536) {                          // W1: (256,256) [k][n]
        int k = i >> 8, n = i & 255;
        float w = W1[i];
        int kb = k >> 5, kq = (k >> 3) & 3, r = k & 7;
        int idx = ((kb * 256 + n) * 4 + kq) * 8 + r;
        unsigned short hi = f2bf(w);
        g_w1hi[idx] = (short)hi;
        g_w1lo[idx] = (short)f2bf(w - bf2f(hi));
    } else {                                  // W2: (256,128) [k][n]
        int j = i - 65536;
        int k = j >> 7, n = j & 127;
        float w = W2[j];
        int kb = k >> 5, kq = (k >> 3) & 3, r = k & 7;
        int idx = ((kb * 128 + n) * 4 + kq) * 8 + r;
        unsigned short hi = f2bf(w);
        g_w2hi[idx] = (short)hi;
        g_w2lo[idx] = (short)f2bf(w - bf2f(hi));
    }
    if (blockIdx.x == 0 && threadIdx.x < 2) {
        const int hh = threadIdx.x;
        float P = 0.f, Q = 0.f, R = 0.f;
        for (int k = 0; k < 64; ++k) {
            const int c = hh * 64 + k;
            const float a = att[c];
            P = fmaf(a, W_l[c], P);
            Q = fmaf(a, W_r[c], Q);
            R = fmaf(a, b_l[c] + b_r[c], R);
        }
        g_lin[hh * 3 + 0] = P;
        g_lin[hh * 3 + 1] = Q;
        g_lin[hh * 3 + 2] = R;
    }
}

// ---------------------------------------------------------------------------
// Edge pass, all 8 timesteps, no atomics.
// ---------------------------------------------------------------------------
__global__ __launch_bounds__(256) void edge_all_kernel(
    const float* __restrict__ W_l, const float* __restrict__ b_l,
    const float* __restrict__ W_r, const float* __restrict__ b_r,
    const float* __restrict__ att)
{
    __shared__ float4 ch4[128];
    const int tid = threadIdx.x;
    if (tid < 128)
        ch4[tid] = make_float4(W_l[tid], W_r[tid], b_l[tid] + b_r[tid], att[tid]);
    __syncthreads();

    const int n    = blockIdx.x * 128 + (tid >> 1);
    const int head = tid & 1;
    const int t    = blockIdx.y;
    if (n >= N_NODES) return;

    const float* xrow = &g_xT[t * N_NODES];
    const float xd = xrow[n];
    const float P = g_lin[head * 3 + 0];
    const float Q = g_lin[head * 3 + 1];
    const float R = g_lin[head * 3 + 2];
    const float4* chh = &ch4[head * 64];

    const int base = g_rowptr[n];
    const int deg  = g_rowptr[n + 1] - base;
    const int tot  = deg + 1;            // +1 = self loop at idx 0

    float den = 0.f, num = 0.f;
    for (int cs = 0; cs < tot; cs += 8) {
        int m = tot - cs; if (m > 8) m = 8;
        float xs[8];
        #pragma unroll
        for (int e = 0; e < 8; ++e) {
            xs[e] = 0.f;
            if (e < m) {
                const int idx = cs + e;
                xs[e] = (idx == 0) ? xd : xrow[g_sorted[base + idx - 1]];
            }
        }
        float ea[8];
        #pragma unroll
        for (int e = 0; e < 8; ++e) ea[e] = 0.f;
        #pragma unroll 4
        for (int c = 0; c < 64; ++c) {
            const float4 f = chh[c];
            const float dpart = fmaf(xd, f.y, f.z);
            #pragma unroll
            for (int e = 0; e < 8; ++e) {
                const float a = fmaf(xs[e], f.x, dpart);
                ea[e] = fmaf(fabsf(a), f.w, ea[e]);
            }
        }
        #pragma unroll
        for (int e = 0; e < 8; ++e) {
            if (e < m) {
                const float ee = fmaf(0.6f, fmaf(xs[e], P, fmaf(xd, Q, R)), 0.4f * ea[e]);
                const float ex = __expf(ee);
                den += ex;
                num = fmaf(ex, xs[e], num);
            }
        }
    }
    g_ndf[((size_t)t * N_NODES + n) * 4 + head]     = den;
    g_ndf[((size_t)t * N_NODES + n) * 4 + 2 + head] = num;
}

// ---------------------------------------------------------------------------
// GRU v2: BN=32, 625 blocks, 512 threads. h in REGISTERS. featA row = 512
// shorts: segments [f0: g0-15 | h: g16-31 | rh: g32-47 | f1: g48-63], XOR
// granule swizzle ^ (node&7) within segment. 2 barriers/step.
// NOTE: plain __launch_bounds__(512) — r5's (512,4) clamped VGPRs to 64 and
// caused catastrophic scratch spill (FETCH 328MB, WRITE 120MB).
// ---------------------------------------------------------------------------
__global__ __launch_bounds__(512) void gru_all_kernel(
    const float* __restrict__ W_l, const float* __restrict__ b_l,
    const float* __restrict__ conv_bias,
    const float* __restrict__ b1, const float* __restrict__ b2,
    float* __restrict__ hout)
{
    __shared__ short featA[BN * 512];   // 32768 B
    __shared__ float swl[128], sbl[128], scb[128], sb1a[128], sb1b[128], sb2[128];

    const int t   = threadIdx.x;
    const int n0g = blockIdx.x * BN;

    if (t < 128) {
        swl[t] = W_l[t]; sbl[t] = b_l[t]; scb[t] = conv_bias[t];
        sb1a[t] = b1[t]; sb1b[t] = b1[128 + t]; sb2[t] = b2[t];
    }
    // zero h segment (granules 16..31), one granule per thread
    {
        const int node = t >> 4;
        const int g    = 16 + (t & 15);
        const int gsw  = g ^ (node & 7);
        *(short8*)&featA[node * 512 + gsw * 8] = (short8)0;
    }
    __syncthreads();   // biases + h-zero visible

    const int wid = t >> 6;
    const int l   = t & 63;
    const int lr  = l & 15;
    const int lk  = l >> 4;
    const int ec  = wid * 16 + lr;      // this wave's column set
    const int pnode = t >> 4;           // phase0 mapping
    const int pg    = t & 15;

    const float ba1 = sb1a[ec], bb1 = sb1b[ec], bb2 = sb2[ec];

    f32x4 hreg[2], ureg[2];
    hreg[0] = (f32x4){0.f, 0.f, 0.f, 0.f};
    hreg[1] = (f32x4){0.f, 0.f, 0.f, 0.f};

    for (int step = 0; step < T_STEPS; ++step) {
        const int fbase = (step & 1) ? 48 : 0;

        // ---- phase0: f for this step -> segment fbase (512 tasks) --------
        {
            const int head = pg >> 3;
            const size_t bi = ((size_t)step * N_NODES + n0g + pnode) * 4;
            const float den = g_ndf[bi + head];
            const float num = g_ndf[bi + 2 + head];
            const float inv = 1.0f / (den + 1e-16f);
            short8 v;
            #pragma unroll
            for (int r = 0; r < 8; ++r) {
                const int c = pg * 8 + r;
                const float z = (num * swl[c] + den * sbl[c]) * inv + scb[c];
                v[r] = (short)f2bf(fsig(z));
            }
            const int gsw = (fbase + pg) ^ (pnode & 7);
            *(short8*)&featA[pnode * 512 + gsw * 8] = v;
        }
        __syncthreads();   // B1: f[p] + h (prev epi2) visible to all

        // ---- GEMM1: M=32, this wave cols ec (r) and 128+ec (u), K=256 ----
        f32x4 acc0[2], acc1[2];
        #pragma unroll
        for (int mf = 0; mf < 2; ++mf) {
            acc0[mf] = (f32x4){ba1, ba1, ba1, ba1};
            acc1[mf] = (f32x4){bb1, bb1, bb1, bb1};
        }
        #pragma unroll
        for (int kb = 0; kb < 8; ++kb) {
            const int glin = kb * 4 + lk;                 // 0..31
            const int gra  = (glin < 16) ? fbase + glin : glin;  // h at 16..31
            short8 ah[2];
            #pragma unroll
            for (int mf = 0; mf < 2; ++mf) {
                const int row = mf * 16 + lr;
                const int g   = gra ^ (row & 7);
                ah[mf] = *(short8*)&featA[row * 512 + g * 8];
            }
            const int bidx0 = ((kb * 256 + ec) * 4 + lk) * 8;
            const int bidx1 = bidx0 + 4096;               // +128 cols
            const short8 bh0 = *(const short8*)&g_w1hi[bidx0];
            const short8 bl0 = *(const short8*)&g_w1lo[bidx0];
            const short8 bh1 = *(const short8*)&g_w1hi[bidx1];
            const short8 bl1 = *(const short8*)&g_w1lo[bidx1];
            #pragma unroll
            for (int mf = 0; mf < 2; ++mf) {
                acc0[mf] = __builtin_amdgcn_mfma_f32_16x16x32_bf16(ah[mf], bh0, acc0[mf], 0, 0, 0);
                acc0[mf] = __builtin_amdgcn_mfma_f32_16x16x32_bf16(ah[mf], bl0, acc0[mf], 0, 0, 0);
                acc1[mf] = __builtin_amdgcn_mfma_f32_16x16x32_bf16(ah[mf], bh1, acc1[mf], 0, 0, 0);
                acc1[mf] = __builtin_amdgcn_mfma_f32_16x16x32_bf16(ah[mf], bl1, acc1[mf], 0, 0, 0);
            }
        }

        // ---- epi1: r,u; rh -> rh segment (packed dword writes) -----------
        #pragma unroll
        for (int mf = 0; mf < 2; ++mf) {
            #pragma unroll
            for (int j = 0; j < 4; ++j) {
                const int row = mf * 16 + lk * 4 + j;
                const float r = fsig(acc0[mf][j]);
                const float u = fsig(acc1[mf][j]);
                ureg[mf][j] = u;
                const float rh = r * hreg[mf][j];
                const float ot = __shfl_xor(rh, 1);
                if ((lr & 1) == 0) {
                    const unsigned pk = (unsigned)f2bf(rh) | ((unsigned)f2bf(ot) << 16);
                    const int g  = (32 + (ec >> 3)) ^ (row & 7);
                    const int ad = row * 512 + g * 8 + (ec & 7);
                    *(unsigned*)&featA[ad] = pk;
                }
            }
        }
        __syncthreads();   // B2: rh visible to all

        // ---- GEMM2: this wave col ec, K=256 ------------------------------
        f32x4 acc2[2];
        #pragma unroll
        for (int mf = 0; mf < 2; ++mf)
            acc2[mf] = (f32x4){bb2, bb2, bb2, bb2};
        #pragma unroll
        for (int kb = 0; kb < 8; ++kb) {
            const int glin = kb * 4 + lk;
            const int gra  = (glin < 16) ? fbase + glin : glin + 16;  // rh at 32..47
            short8 ah[2];
            #pragma unroll
            for (int mf = 0; mf < 2; ++mf) {
                const int row = mf * 16 + lr;
                const int g   = gra ^ (row & 7);
                ah[mf] = *(short8*)&featA[row * 512 + g * 8];
            }
            const int bidx = ((kb * 128 + ec) * 4 + lk) * 8;
            const short8 bh = *(const short8*)&g_w2hi[bidx];
            const short8 bl = *(const short8*)&g_w2lo[bidx];
            #pragma unroll
            for (int mf = 0; mf < 2; ++mf) {
                acc2[mf] = __builtin_amdgcn_mfma_f32_16x16x32_bf16(ah[mf], bh, acc2[mf], 0, 0, 0);
                acc2[mf] = __builtin_amdgcn_mfma_f32_16x16x32_bf16(ah[mf], bl, acc2[mf], 0, 0, 0);
            }
        }

        // ---- epi2: c=tanh; h_new = c + u*(h-c); h -> h segment -----------
        #pragma unroll
        for (int mf = 0; mf < 2; ++mf) {
            #pragma unroll
            for (int j = 0; j < 4; ++j) {
                const int row = mf * 16 + lk * 4 + j;
                const float c  = tanhf(acc2[mf][j]);
                const float hn = fmaf(ureg[mf][j], hreg[mf][j] - c, c);
                hreg[mf][j] = hn;
                if (step < T_STEPS - 1) {
                    const float ot = __shfl_xor(hn, 1);
                    if ((lr & 1) == 0) {
                        const unsigned pk = (unsigned)f2bf(hn) | ((unsigned)f2bf(ot) << 16);
                        const int g  = (16 + (ec >> 3)) ^ (row & 7);
                        const int ad = row * 512 + g * 8 + (ec & 7);
                        *(unsigned*)&featA[ad] = pk;
                    }
                } else {
                    hout[(size_t)(n0g + row) * HID + ec] = hn;
                }
            }
        }
        // no barrier: next phase0 writes f[p^1] (disjoint); B1 fences all.
    }
}

// ---------------------------------------------------------------------------
extern "C" void kernel_launch(void* const* d_in, const int* in_sizes, int n_in,
                              void* d_out, int out_size, void* d_ws, size_t ws_size,
                              hipStream_t stream) {
    const float* x   = (const float*)d_in[0];
    const void*  ei  = d_in[1];
    // d_in[2] edge_weight: unused by the reference
    const float* W_l = (const float*)d_in[3];
    const float* b_l = (const float*)d_in[4];
    const float* W_r = (const float*)d_in[5];
    const float* b_r = (const float*)d_in[6];
    const float* att = (const float*)d_in[7];
    const float* cb  = (const float*)d_in[8];
    const float* W1  = (const float*)d_in[9];
    const float* b1  = (const float*)d_in[10];
    const float* W2  = (const float*)d_in[11];
    const float* b2  = (const float*)d_in[12];

    float* h = (float*)d_out;
    (void)d_ws; (void)ws_size;

    detect_kernel<<<1, 1, 0, stream>>>((const unsigned int*)ei);
    init_kernel<<<(T_STEPS * N_NODES + 255) / 256, 256, 0, stream>>>(x, ei);
    hist_kernel<<<(E_EDGES + 255) / 256, 256, 0, stream>>>(ei);
    scan_kernel<<<1, 1024, 0, stream>>>();
    scatter_kernel<<<(E_EDGES + 255) / 256, 256, 0, stream>>>(ei);
    prep_kernel<<<384, 256, 0, stream>>>(W1, W2, W_l, b_l, W_r, b_r, att);
    edge_all_kernel<<<dim3(157, T_STEPS), 256, 0, stream>>>(W_l, b_l, W_r, b_r, att);
    gru_all_kernel<<<N_NODES / BN, 512, 0, stream>>>(W_l, b_l, cb, b1, b2, h);
}